// Round 7
// baseline (155.071 us; speedup 1.0000x reference)
//
#include <hip/hip_runtime.h>
#include <cstddef>
#include <cstdint>

// Problem constants: B=2, T=2048, C=1024, H=16, hs=64
#define B_N 2
#define T_N 2048
#define C_N 1024
#define H_N 16
#define HS_N 64
#define M_N (B_N * T_N)   // 4096

typedef __attribute__((ext_vector_type(8))) short bf16x8;   // 8 bf16 = 4 VGPRs
typedef __attribute__((ext_vector_type(4))) float f32x4;

// 0.125 (hs^-0.5) * log2(e): folded into Wq so attention uses exp2 directly
#define QSCALE 0.18033688011112042f

__device__ __forceinline__ ushort f2bf(float f) {
    union { float f; uint32_t u; } v; v.f = f;
    uint32_t r = v.u + 0x7fffu + ((v.u >> 16) & 1u);   // round-nearest-even
    return (ushort)(r >> 16);
}

// async global->LDS, 16B per lane; lds base must be wave-uniform
#define GLL16(g, l)                                                         \
    __builtin_amdgcn_global_load_lds(                                       \
        (const __attribute__((address_space(1))) unsigned int*)(g),         \
        (__attribute__((address_space(3))) unsigned int*)(l), 16, 0, 0)

// ---------------------------------------------------------------------------
// Fused fp32->bf16 convert: x | Wq(*QSCALE) | Wp | Wk | Wv (one launch).
// ---------------------------------------------------------------------------
__global__ void cvt_all_kernel(const float* __restrict__ x,
                               const float* __restrict__ Wq,
                               const float* __restrict__ Wp,
                               const float* __restrict__ Wk,
                               const float* __restrict__ Wv,
                               ushort* __restrict__ xb,
                               ushort* __restrict__ Wqb,
                               ushort* __restrict__ Wpb,
                               ushort* __restrict__ Wkvb) {
    const int S0 = M_N * C_N / 4;
    const int S1 = S0 + C_N * C_N / 4;
    const int S2 = S1 + C_N * C_N / 4;
    const int S3 = S2 + HS_N * C_N / 4;
    const int S4 = S3 + HS_N * C_N / 4;
    const int stride = gridDim.x * blockDim.x;
    for (int i = blockIdx.x * blockDim.x + threadIdx.x; i < S4; i += stride) {
        const float* src; ushort* dst; int j; float sc = 1.f;
        if (i < S0)      { src = x;  dst = xb;   j = i; }
        else if (i < S1) { src = Wq; dst = Wqb;  j = i - S0; sc = QSCALE; }
        else if (i < S2) { src = Wp; dst = Wpb;  j = i - S1; }
        else if (i < S3) { src = Wk; dst = Wkvb; j = i - S2; }
        else             { src = Wv; dst = Wkvb + HS_N * C_N; j = i - S3; }
        const float4 f = ((const float4*)src)[j];
        ushort4 o;
        o.x = f2bf(f.x * sc); o.y = f2bf(f.y * sc);
        o.z = f2bf(f.z * sc); o.w = f2bf(f.w * sc);
        ((ushort4*)dst)[j] = o;
    }
}

// ---------------------------------------------------------------------------
// bf16 MFMA GEMM, BM=64, BN=128, BK=64, 256 threads (4 waves 2x2, 32x64 each).
// vs round-6's 64x64: mfma:ds_read ratio 1:1 -> 1.33:1 (16 mfma / 12 b128 per
// wave-iter) while keeping the grid large (512-576 blocks = 2-2.25/CU so
// GLL16 vmcnt drains overlap across resident blocks; 128^2 would collapse to
// 1.1/CU = m102's 320 TF regime).
// LDS unpadded, chunk XOR-swizzled by (row&7) (round-6-verified).
// MODE 0: fp32 out + bias.  MODE 1: bf16 out for n0<1024; the 9th n-tile
// (n0=1024) holds K (cols 0..63 -> kb natural) and V (64..127 -> vbt
// TRANSPOSED [b][d][t], packed ushort4 = 4 consecutive t).
// ---------------------------------------------------------------------------
template <int MODE>
__global__ __launch_bounds__(256, 2) void gemm_bf16(
    const ushort* __restrict__ A,   // [M][K] bf16
    const ushort* __restrict__ W,   // [Ntot][K] bf16
    const float* __restrict__ bias, // MODE 0 only
    void* __restrict__ Cout,        // [M][1024] fp32 (MODE 0) / bf16 (MODE 1)
    ushort* __restrict__ kb,        // MODE 1: [4096][64]
    ushort* __restrict__ vbt,       // MODE 1: [2][64][2048]
    int K)
{
    __shared__ ushort As[64 * 64];    // 8 KB
    __shared__ ushort Bs[128 * 64];   // 16 KB
    const int m0 = blockIdx.x * 64;
    const int n0 = blockIdx.y * 128;
    const int tid = threadIdx.x;
    const int wid = tid >> 6;
    const int lane = tid & 63;
    const int ln = lane & 15;
    const int quad = lane >> 4;
    const int wm = wid >> 1, wn = wid & 1;   // wave = rows wm*32+, cols wn*64+

    f32x4 acc[2][4];
    #pragma unroll
    for (int i = 0; i < 2; ++i)
        #pragma unroll
        for (int j = 0; j < 4; ++j)
            acc[i][j] = (f32x4){0.f, 0.f, 0.f, 0.f};

    const int srow = lane >> 3;          // 0..7 row within 8-row segment
    const int schk = (lane & 7) ^ srow;  // fetched chunk (row&7 == srow)

    for (int k0 = 0; k0 < K; k0 += 64) {
        __syncthreads();   // prior iteration's LDS reads complete
        #pragma unroll
        for (int t = 0; t < 2; ++t) {    // A: 8 segments of 8 rows
            const int seg = wid * 2 + t;
            GLL16(A + (size_t)(m0 + seg * 8 + srow) * K + k0 + schk * 8,
                  As + seg * 512);
        }
        #pragma unroll
        for (int t = 0; t < 4; ++t) {    // B: 16 segments of 8 rows
            const int seg = wid * 4 + t;
            GLL16(W + (size_t)(n0 + seg * 8 + srow) * K + k0 + schk * 8,
                  Bs + seg * 512);
        }
        __syncthreads();   // drains vmcnt (GLL16 counted there)

        #pragma unroll
        for (int hh = 0; hh < 2; ++hh) {
            bf16x8 af[2], bf[4];
            const int sw = ln & 7;
            #pragma unroll
            for (int i = 0; i < 2; ++i) {
                const int row = wm * 32 + i * 16 + ln;
                af[i] = *(const bf16x8*)&As[row * 64 + (((hh * 4 + quad) ^ sw) * 8)];
            }
            #pragma unroll
            for (int j = 0; j < 4; ++j) {
                const int row = wn * 64 + j * 16 + ln;
                bf[j] = *(const bf16x8*)&Bs[row * 64 + (((hh * 4 + quad) ^ sw) * 8)];
            }
            #pragma unroll
            for (int i = 0; i < 2; ++i)
                #pragma unroll
                for (int j = 0; j < 4; ++j)
                    acc[i][j] = __builtin_amdgcn_mfma_f32_16x16x32_bf16(
                        af[i], bf[j], acc[i][j], 0, 0, 0);
        }
    }

    if (MODE == 1 && n0 >= C_N) {        // kv tile: K cols 0..63, V 64..127
        #pragma unroll
        for (int i = 0; i < 2; ++i) {
            const int row0 = m0 + wm * 32 + i * 16 + quad * 4;
            #pragma unroll
            for (int j = 0; j < 4; ++j) {
                const int c2 = wn * 64 + j * 16 + ln;
                if (c2 >= 64) {
                    // vbt[b][d][t], 4 regs = 4 consecutive t
                    const int d = c2 - 64;
                    const int b = row0 >> 11;
                    const int t0 = row0 & 2047;
                    ushort4 pk;
                    pk.x = f2bf(acc[i][j][0]); pk.y = f2bf(acc[i][j][1]);
                    pk.z = f2bf(acc[i][j][2]); pk.w = f2bf(acc[i][j][3]);
                    *(ushort4*)&vbt[((size_t)b * 64 + d) * T_N + t0] = pk;
                } else {
                    #pragma unroll
                    for (int reg = 0; reg < 4; ++reg)
                        kb[(size_t)(row0 + reg) * 64 + c2] = f2bf(acc[i][j][reg]);
                }
            }
        }
        return;
    }

    #pragma unroll
    for (int i = 0; i < 2; ++i) {
        #pragma unroll
        for (int j = 0; j < 4; ++j) {
            const int col = n0 + wn * 64 + j * 16 + ln;
            const float bv = (MODE == 0) ? bias[col] : 0.f;
            #pragma unroll
            for (int reg = 0; reg < 4; ++reg) {
                const int row = m0 + wm * 32 + i * 16 + quad * 4 + reg;
                const float v = acc[i][j][reg] + bv;
                if (MODE == 0)
                    ((float*)Cout)[(size_t)row * C_N + col] = v;
                else
                    ((ushort*)Cout)[(size_t)row * C_N + col] = f2bf(v);
            }
        }
    }
}

// ---------------------------------------------------------------------------
// Flash causal MQA attention, bf16 MFMA, m=0 softmax, S^T formulation
// (round-6-verified math), now with LDS DOUBLE-BUFFERED K/V:
// one barrier per k-tile; staging ds_writes overlap the previous tile's
// compute; global prefetch issued a full iteration before its ds_write.
// Grid 32bh x 16 pairs = 512 blocks (2/CU). Block owns 64-row q-tiles
// A=p (kt<=p) and B=31-p (always): 33 subtile-computes per wave, uniform.
// ---------------------------------------------------------------------------
__global__ __launch_bounds__(256, 2) void attn_mfma_kernel(
    const ushort* __restrict__ qb,
    const ushort* __restrict__ kb,    // [4096][64]
    const ushort* __restrict__ vbt,   // [2][64][2048]
    ushort* __restrict__ yb)
{
    __shared__ ushort Ks[2][64][72];   // [buf][kk][d]
    __shared__ ushort Vt[2][64][72];   // [buf][d][kk]
    __shared__ ushort Ps[4][16][72];   // per-wave [q][kk]

    const int bh = blockIdx.x;
    const int b = bh >> 4, h = bh & 15;
    const int p = blockIdx.y;          // 0..15
    const int qA0 = p * 64;            // light tile (active kt <= p)
    const int qB0 = (31 - p) * 64;     // heavy tile (always active)
    const int tid = threadIdx.x;
    const int wid = tid >> 6;
    const int lane = tid & 63;
    const int ln = lane & 15;
    const int quad = lane >> 4;

    // Q fragments, B-operand layout: Q[q=ln][d = half*32 + quad*8 + j]
    const ushort* qstrip = qb + (size_t)b * T_N * C_N + (size_t)h * T_N * HS_N;
    const size_t rB = (size_t)(qB0 + wid * 16 + ln) * HS_N;
    const size_t rA = (size_t)(qA0 + wid * 16 + ln) * HS_N;
    bf16x8 qfB[2], qfA[2];
    qfB[0] = *(const bf16x8*)(qstrip + rB + quad * 8);
    qfB[1] = *(const bf16x8*)(qstrip + rB + 32 + quad * 8);
    qfA[0] = *(const bf16x8*)(qstrip + rA + quad * 8);
    qfA[1] = *(const bf16x8*)(qstrip + rA + 32 + quad * 8);

    f32x4 oB[4], oA[4];
    float lB = 0.f, lA = 0.f;
    #pragma unroll
    for (int nt = 0; nt < 4; ++nt) {
        oB[nt] = (f32x4){0.f, 0.f, 0.f, 0.f};
        oA[nt] = (f32x4){0.f, 0.f, 0.f, 0.f};
    }

    const ushort* kbase = kb + (size_t)b * T_N * HS_N;
    const ushort* vtbase = vbt + (size_t)b * HS_N * T_N;
    const int rs = tid >> 3;   // 0..31 staging row
    const int cs = tid & 7;    // 0..7 staging 16B chunk

    const int nkt = 32 - p;

    int4 kc0, kc1, vc0, vc1;
    {   // tile 0 -> regs -> buf0
        kc0 = *(const int4*)(kbase + (size_t)rs * HS_N + cs * 8);
        kc1 = *(const int4*)(kbase + (size_t)(rs + 32) * HS_N + cs * 8);
        vc0 = *(const int4*)(vtbase + (size_t)rs * T_N + cs * 8);
        vc1 = *(const int4*)(vtbase + (size_t)(rs + 32) * T_N + cs * 8);
        *(int4*)&Ks[0][rs][cs * 8] = kc0;
        *(int4*)&Ks[0][rs + 32][cs * 8] = kc1;
        *(int4*)&Vt[0][rs][cs * 8] = vc0;
        *(int4*)&Vt[0][rs + 32][cs * 8] = vc1;
    }
    if (nkt > 1) {   // prefetch tile 1
        kc0 = *(const int4*)(kbase + (size_t)(64 + rs) * HS_N + cs * 8);
        kc1 = *(const int4*)(kbase + (size_t)(64 + rs + 32) * HS_N + cs * 8);
        vc0 = *(const int4*)(vtbase + (size_t)rs * T_N + 64 + cs * 8);
        vc1 = *(const int4*)(vtbase + (size_t)(rs + 32) * T_N + 64 + cs * 8);
    }
    __syncthreads();

    bf16x8 kf[4][2], vf[4][2];

    // one 64-key tile for one 16-q subtile
    auto tile_compute = [&](const bf16x8* qf, f32x4* o, float& l,
                            int qt0, int k0) {
        const int qs0 = qt0 + wid * 16;
        const int qg = qs0 + ln;          // this lane's q-column
        f32x4 sc[4];
        #pragma unroll
        for (int nt = 0; nt < 4; ++nt) {
            sc[nt] = (f32x4){0.f, 0.f, 0.f, 0.f};
            sc[nt] = __builtin_amdgcn_mfma_f32_16x16x32_bf16(
                kf[nt][0], qf[0], sc[nt], 0, 0, 0);
            sc[nt] = __builtin_amdgcn_mfma_f32_16x16x32_bf16(
                kf[nt][1], qf[1], sc[nt], 0, 0, 0);
        }
        const bool dg = (k0 + 63 > qs0);
        #pragma unroll
        for (int nt = 0; nt < 4; ++nt) {
            ushort pk[4];
            #pragma unroll
            for (int reg = 0; reg < 4; ++reg) {
                const int key = k0 + nt * 16 + quad * 4 + reg;
                float sv = sc[nt][reg];
                if (dg && key > qg) sv = -1e30f;
                const float pe = __builtin_amdgcn_exp2f(sv);
                l += pe;
                pk[reg] = f2bf(pe);
            }
            *(uint2*)&Ps[wid][ln][nt * 16 + quad * 4] = *(const uint2*)pk;
        }
        #pragma unroll
        for (int ks2 = 0; ks2 < 2; ++ks2) {
            const bf16x8 pf = *(const bf16x8*)&Ps[wid][ln][ks2 * 32 + quad * 8];
            #pragma unroll
            for (int nt = 0; nt < 4; ++nt)
                o[nt] = __builtin_amdgcn_mfma_f32_16x16x32_bf16(
                    pf, vf[nt][ks2], o[nt], 0, 0, 0);
        }
    };

    for (int kt = 0; kt < nkt; ++kt) {
        const int k0 = kt * 64;
        const int cur = kt & 1, nxt = cur ^ 1;
        if (kt + 1 < nkt) {   // regs hold tile kt+1 -> write to other buffer
            *(int4*)&Ks[nxt][rs][cs * 8] = kc0;
            *(int4*)&Ks[nxt][rs + 32][cs * 8] = kc1;
            *(int4*)&Vt[nxt][rs][cs * 8] = vc0;
            *(int4*)&Vt[nxt][rs + 32][cs * 8] = vc1;
        }
        if (kt + 2 < nkt) {   // prefetch tile kt+2 (one iter of latency cover)
            const int kn = k0 + 128;
            kc0 = *(const int4*)(kbase + (size_t)(kn + rs) * HS_N + cs * 8);
            kc1 = *(const int4*)(kbase + (size_t)(kn + rs + 32) * HS_N + cs * 8);
            vc0 = *(const int4*)(vtbase + (size_t)rs * T_N + kn + cs * 8);
            vc1 = *(const int4*)(vtbase + (size_t)(rs + 32) * T_N + kn + cs * 8);
        }
        // shared K/V fragments for this k-tile (read once, both subtiles)
        #pragma unroll
        for (int nt = 0; nt < 4; ++nt) {
            kf[nt][0] = *(const bf16x8*)&Ks[cur][nt * 16 + ln][quad * 8];
            kf[nt][1] = *(const bf16x8*)&Ks[cur][nt * 16 + ln][32 + quad * 8];
            vf[nt][0] = *(const bf16x8*)&Vt[cur][nt * 16 + ln][quad * 8];
            vf[nt][1] = *(const bf16x8*)&Vt[cur][nt * 16 + ln][32 + quad * 8];
        }
        tile_compute(qfB, oB, lB, qB0, k0);
        if (kt <= p)
            tile_compute(qfA, oA, lA, qA0, k0);
        __syncthreads();   // all waves done reading cur / writing nxt
    }

    // epilogue: l lives per-lane at q=ln; reduce across quads, broadcast to
    // the C-layout row owners, write y = o / l
    #pragma unroll
    for (int t = 0; t < 2; ++t) {
        float l = t ? lA : lB;
        const f32x4* o = t ? oA : oB;
        const int qt0 = t ? qA0 : qB0;
        l += __shfl_xor(l, 16);
        l += __shfl_xor(l, 32);   // all lanes hold full l for q = ln
        #pragma unroll
        for (int reg = 0; reg < 4; ++reg) {
            const float inv = 1.0f / __shfl(l, quad * 4 + reg);
            const int qg = qt0 + wid * 16 + quad * 4 + reg;
            ushort* yrow = yb + (size_t)b * T_N * C_N + (size_t)qg * C_N
                           + h * HS_N;
            #pragma unroll
            for (int nt = 0; nt < 4; ++nt)
                yrow[nt * 16 + ln] = f2bf(o[nt][reg] * inv);
        }
    }
}

// ---------------------------------------------------------------------------
extern "C" void kernel_launch(void* const* d_in, const int* in_sizes, int n_in,
                              void* d_out, int out_size, void* d_ws, size_t ws_size,
                              hipStream_t stream) {
    const float* x  = (const float*)d_in[0];
    const float* Wk = (const float*)d_in[1];
    const float* Wv = (const float*)d_in[2];
    const float* Wq = (const float*)d_in[3];
    const float* Wp = (const float*)d_in[4];
    const float* bp = (const float*)d_in[5];
    float* out = (float*)d_out;

    ushort* xb   = (ushort*)d_ws;                     // [4096][1024]
    ushort* qb   = xb   + (size_t)M_N * C_N;          // [4096][1024]
    ushort* yb   = qb   + (size_t)M_N * C_N;          // [4096][1024]
    ushort* kbw  = yb   + (size_t)M_N * C_N;          // [4096][64]
    ushort* vbt  = kbw  + (size_t)M_N * HS_N;         // [2][64][2048]
    ushort* Wqb  = vbt  + (size_t)B_N * HS_N * T_N;   // [1024][1024] (scaled)
    ushort* Wkvb = Wqb  + (size_t)C_N * C_N;          // [128][1024], after Wq
    ushort* Wpb  = Wkvb + (size_t)128 * C_N;          // [1024][1024]

    cvt_all_kernel<<<1024, 256, 0, stream>>>(x, Wq, Wp, Wk, Wv,
                                             xb, Wqb, Wpb, Wkvb);

    // fused q + k + v projection: W' = [Wq(scaled); Wk; Wv] (1152 rows)
    // n-tiles 0..7 -> qb; tile 8 -> kbw (natural) + vbt (transposed)
    gemm_bf16<1><<<dim3(M_N / 64, (C_N + 128) / 128), 256, 0, stream>>>(
        xb, Wqb, nullptr, qb, kbw, vbt, C_N);

    // attention -> yb bf16 [4096][1024]; paired 64-row tiles (32bh x 16)
    attn_mfma_kernel<<<dim3(B_N * H_N, 16), 256, 0, stream>>>(qb, kbw, vbt, yb);

    // out = y @ Wp^T + bp -> fp32
    gemm_bf16<0><<<dim3(M_N / 64, C_N / 128), 256, 0, stream>>>(
        yb, Wpb, bp, out, nullptr, nullptr, C_N);
}